// Round 6
// baseline (225.079 us; speedup 1.0000x reference)
//
#include <hip/hip_runtime.h>
#include <math.h>

#define BS 16
#define S 512
#define D 1024
#define H 16
#define DK 64
#define HALF 8

typedef __attribute__((ext_vector_type(8))) short short8v;
typedef __attribute__((ext_vector_type(4))) float f32x4;
typedef unsigned short ushort_t;

#define L2E 1.4426950408889634f
#define SC_STD (0.125f * L2E)
#define SC_PEN (-0.0125f * L2E)

__device__ __forceinline__ ushort_t f2bf(float f) {
  union { float f; unsigned u; } v; v.f = f;
  unsigned r = v.u + 0x7fffu + ((v.u >> 16) & 1u);
  return (ushort_t)(r >> 16);
}
__device__ __forceinline__ unsigned packbf(float a, float b) {
  return (unsigned)f2bf(a) | ((unsigned)f2bf(b) << 16);
}
__device__ __forceinline__ float bf2f(ushort_t u) {
  union { unsigned u; float f; } v; v.u = ((unsigned)u) << 16;
  return v.f;
}
__device__ __forceinline__ unsigned cvtpk(float lo, float hi) {
  unsigned r;
  asm("v_cvt_pk_bf16_f32 %0, %1, %2" : "=v"(r) : "v"(lo), "v"(hi));
  return r;
}

__device__ __forceinline__ void gload16(const void* g, void* l) {
  __builtin_amdgcn_global_load_lds(
      (const __attribute__((address_space(1))) unsigned int*)g,
      (__attribute__((address_space(3))) unsigned int*)l, 16, 0, 0);
}

// ---------------------------------------------------------------------------
// f32 -> bf16 convert, 8 elems/thread
// ---------------------------------------------------------------------------
__global__ __launch_bounds__(256) void cvt_bf16(const float* __restrict__ in,
                                                ushort_t* __restrict__ out,
                                                int n8) {
  const int i = blockIdx.x * 256 + threadIdx.x;
  if (i >= n8) return;
  const float4 a = *(const float4*)(in + (size_t)i * 8);
  const float4 b = *(const float4*)(in + (size_t)i * 8 + 4);
  union { short8v v; unsigned u[4]; } t;
  t.u[0] = packbf(a.x, a.y);
  t.u[1] = packbf(a.z, a.w);
  t.u[2] = packbf(b.x, b.y);
  t.u[3] = packbf(b.z, b.w);
  *(short8v*)(out + (size_t)i * 8) = t.v;
}

// ---------------------------------------------------------------------------
// bf16 MFMA GEMM (unchanged): C[8192,1024] = A * B^T + bias
// ---------------------------------------------------------------------------
template <int EPI>
__global__ __launch_bounds__(256) void gemm_mfma(
    const ushort_t* __restrict__ A, const ushort_t* __restrict__ B,
    const float* __restrict__ bias, void* __restrict__ Cout) {
  const int tid = threadIdx.x;
  const int lane = tid & 63, wid = tid >> 6;
  const int wr = wid >> 1, wc = wid & 1;
  const int lq = lane & 15, g = lane >> 4;
  const int bn = blockIdx.x;
  const int bm = blockIdx.y;

  __shared__ __align__(16) ushort_t sA[128 * 64];
  __shared__ __align__(16) ushort_t sB[128 * 64];

  f32x4 acc[4][4];
#pragma unroll
  for (int i = 0; i < 4; i++)
#pragma unroll
    for (int j = 0; j < 4; j++) acc[i][j] = (f32x4){0.f, 0.f, 0.f, 0.f};

  for (int k0 = 0; k0 < 1024; k0 += 64) {
#pragma unroll
    for (int is = 0; is < 4; ++is) {
      const int gi = is * 256 + tid;
      const int row = gi >> 3, slot = gi & 7;
      const int sslot = slot ^ (row & 7);
      const ushort_t* srcA =
          A + (size_t)(bm * 128 + row) * 1024 + k0 + sslot * 8;
      const ushort_t* srcB =
          B + (size_t)(bn * 128 + row) * 1024 + k0 + sslot * 8;
      gload16(srcA, &sA[(is * 256 + wid * 64) * 8]);
      gload16(srcB, &sB[(is * 256 + wid * 64) * 8]);
    }
    __syncthreads();
#pragma unroll
    for (int ks = 0; ks < 2; ++ks) {
      short8v af[4], bf[4];
#pragma unroll
      for (int i = 0; i < 4; ++i) {
        const int arow = wr * 64 + i * 16 + lq;
        af[i] = *(const short8v*)&sA[arow * 64 + (((ks * 4 + g) ^ (arow & 7)) * 8)];
        const int brow = wc * 64 + i * 16 + lq;
        bf[i] = *(const short8v*)&sB[brow * 64 + (((ks * 4 + g) ^ (brow & 7)) * 8)];
      }
#pragma unroll
      for (int i = 0; i < 4; ++i)
#pragma unroll
        for (int j = 0; j < 4; ++j)
          acc[i][j] =
              __builtin_amdgcn_mfma_f32_16x16x32_bf16(af[i], bf[j], acc[i][j], 0, 0, 0);
    }
    __syncthreads();
  }

#pragma unroll
  for (int j = 0; j < 4; ++j) {
    const int n = bn * 128 + wc * 64 + j * 16 + lq;
    const float bv = bias[n];
#pragma unroll
    for (int i = 0; i < 4; ++i) {
      const int mb = bm * 128 + wr * 64 + i * 16 + g * 4;
      if (EPI == 0) {
        ushort_t* C = (ushort_t*)Cout;
#pragma unroll
        for (int r = 0; r < 4; ++r) {
          const int m = mb + r;
          const float c = acc[i][j][r] + bv;
          C[((((size_t)(m >> 9) * H + (n >> 6)) * S + (m & 511)) * DK) +
            (n & 63)] = f2bf(c);
        }
      } else if (EPI == 1) {
        ushort_t* C = (ushort_t*)Cout;
        const int bb = mb >> 9, s0 = mb & 511;
        uint2 u;
        u.x = packbf(acc[i][j][0] + bv, acc[i][j][1] + bv);
        u.y = packbf(acc[i][j][2] + bv, acc[i][j][3] + bv);
        *(uint2*)(C + (((size_t)bb * H + (n >> 6)) * DK + (n & 63)) * S + s0) = u;
      } else {
        float* C = (float*)Cout;
#pragma unroll
        for (int r = 0; r < 4; ++r)
          C[(size_t)(mb + r) * 1024 + n] = acc[i][j][r] + bv;
      }
    }
  }
}

// ---------------------------------------------------------------------------
// psi transform on bf16 (in place), heads HALF..H-1; emits per-row float4
// (sum(x^2, d<63), y^2, sqrt(1-y^2+eps), 0) for the penumbral score math.
// ---------------------------------------------------------------------------
__global__ __launch_bounds__(256) void psi_kernel(ushort_t* __restrict__ X,
                                                  float4* __restrict__ Pn) {
  const int s = blockIdx.x * 4 + (threadIdx.x >> 6);
  const int hh = blockIdx.y, b = blockIdx.z;
  const int h = HALF + hh;
  ushort_t* row = X + (((size_t)b * H + h) * S + s) * DK;
  const int t = threadIdx.x & 63;
  const float v = bf2f(row[t]);
  const float last = __shfl(v, 63, 64);
  const float y = 1.0f / (1.0f + expf(-last));
  const float xv = (t < 63) ? v * y : y;
  const ushort_t bvv = f2bf(xv);
  row[t] = bvv;
  const float xr = bf2f(bvv);
  float sq = (t < 63) ? xr * xr : 0.0f;
#pragma unroll
  for (int off = 32; off; off >>= 1) sq += __shfl_xor(sq, off, 64);
  if (t == 0)
    Pn[((size_t)b * HALF + hh) * S + s] =
        make_float4(sq, y * y, sqrtf(1.0f - y * y + 1e-6f), 0.0f);
}

// ---------------------------------------------------------------------------
// One q-tile update vs the currently staged 64-k tile. Log2-domain softmax.
// MASK: only the diagonal k-tile needs causal masking.
// ---------------------------------------------------------------------------
template <bool MASK>
__device__ __forceinline__ void attn_tile(
    const char* sKb, const char* sVb, const float4* sPn, const short8v* qf,
    float qn, float qy2, float xqy, bool pen, float slopeL, int qg, int kt0,
    int lq, int g, f32x4* o, float& m, float& lacc) {
  float p[4][4];
  float tmax = -1e30f;
#pragma unroll
  for (int t4 = 0; t4 < 4; ++t4) {
    f32x4 acc = (f32x4){0.f, 0.f, 0.f, 0.f};
    const int row = t4 * 16 + lq;
#pragma unroll
    for (int c = 0; c < 2; ++c) {
      const short8v ka =
          *(const short8v*)(sKb + row * 128 + (((c * 4 + g) ^ (row & 7)) * 16));
      acc = __builtin_amdgcn_mfma_f32_16x16x32_bf16(ka, qf[c], acc, 0, 0, 0);
    }
#pragma unroll
    for (int r = 0; r < 4; ++r) {
      const int kg = kt0 + t4 * 16 + g * 4 + r;
      const float abL = slopeL * (float)(qg - kg);
      float s;
      if (!pen) {
        s = acc[r] * SC_STD + abL;
      } else {
        const float4 kp = sPn[t4 * 16 + g * 4 + r];
        const float kn = kp.x, ky2 = kp.y, xky = kp.z;
        const float d2 = qn + kn - 2.0f * acc[r];
        const float tt = fmaxf(d2, 0.0f) + 1e-12f;
        const float rs = rsqrtf(tt);
        const float pd = tt * rs;  // = sqrt(tt)
        const float tmp = (xqy + xky - pd) * 0.5f;
        const float lca = fmaxf(fmaxf(qy2, ky2), 1.0f - tmp * tmp);
        const float num = (d2 + ky2 - qy2) * (0.5f * rs);
        const float lout = num * num + qy2;
        const float dxy = pd - xqy;
        const bool ex = (pd <= xqy) || (dxy * dxy + ky2 <= 1.0f);
        s = (ex ? lca : lout) * SC_PEN + abL;
      }
      if (MASK && kg >= qg) s = -1e30f;
      p[t4][r] = s;
      tmax = fmaxf(tmax, s);
    }
  }
  tmax = fmaxf(tmax, __shfl_xor(tmax, 16, 64));
  tmax = fmaxf(tmax, __shfl_xor(tmax, 32, 64));
  const float mnew = fmaxf(m, tmax);
  if (__any(mnew > m)) {  // diagonal-first order: usually only taken once
    const float fsc = exp2f(m - mnew);
#pragma unroll
    for (int dt = 0; dt < 4; ++dt) o[dt] *= fsc;
    lacc *= fsc;
    m = mnew;
  }
  float ls = 0.f;
#pragma unroll
  for (int t4 = 0; t4 < 4; ++t4)
#pragma unroll
    for (int r = 0; r < 4; ++r) {
      float pv = exp2f(p[t4][r] - m);
      if (MASK && p[t4][r] < -1e29f) pv = 0.f;
      p[t4][r] = pv;
      ls += pv;
    }
  ls += __shfl_xor(ls, 16, 64);
  ls += __shfl_xor(ls, 32, 64);
  lacc += ls;

  unsigned pk0[4], pk1[4];
#pragma unroll
  for (int t4 = 0; t4 < 4; ++t4) {
    pk0[t4] = cvtpk(p[t4][0], p[t4][1]);
    pk1[t4] = cvtpk(p[t4][2], p[t4][3]);
  }
  const int s0 = lq | (((g * 2) & 3) << 4);
  const int s1 = lq | (((g * 2 + 1) & 3) << 4);
  const bool hi = (g >= 2);
#pragma unroll
  for (int c = 0; c < 2; ++c) {
    const unsigned a0 = (unsigned)__shfl((int)pk0[2 * c], s0, 64);
    const unsigned b0 = (unsigned)__shfl((int)pk0[2 * c + 1], s0, 64);
    const unsigned a1 = (unsigned)__shfl((int)pk1[2 * c], s0, 64);
    const unsigned b1 = (unsigned)__shfl((int)pk1[2 * c + 1], s0, 64);
    const unsigned a2 = (unsigned)__shfl((int)pk0[2 * c], s1, 64);
    const unsigned b2 = (unsigned)__shfl((int)pk0[2 * c + 1], s1, 64);
    const unsigned a3 = (unsigned)__shfl((int)pk1[2 * c], s1, 64);
    const unsigned b3 = (unsigned)__shfl((int)pk1[2 * c + 1], s1, 64);
    union { short8v v; unsigned u[4]; } pb;
    pb.u[0] = hi ? b0 : a0;
    pb.u[1] = hi ? b1 : a1;
    pb.u[2] = hi ? b2 : a2;
    pb.u[3] = hi ? b3 : a3;
#pragma unroll
    for (int dt = 0; dt < 4; ++dt) {
      const int vr = dt * 16 + lq;
      const short8v va =
          *(const short8v*)(sVb + vr * 128 + (((c * 4 + g) ^ (vr & 7)) * 16));
      o[dt] = __builtin_amdgcn_mfma_f32_16x16x32_bf16(va, pb.v, o[dt], 0, 0, 0);
    }
  }
}

// ---------------------------------------------------------------------------
// Flash attention: block = (q-pair qp/{7-qp}, h, b). 4 waves x 16 q-rows,
// descending causal k-tiles shared by both q-tiles; diagonal tiles use the
// MASK instantiation, interior tiles skip all mask VALU. XCD-swizzled grid.
// __launch_bounds__(256,2): 256-reg cap = spill-free (R4: cap 128 spilled
// 300MB; R5: uncapped went >256 regs -> 1.2 waves/SIMD). 2 waves/SIMD target.
// ---------------------------------------------------------------------------
__global__ __launch_bounds__(256, 2) void attn_mfma(
    const ushort_t* __restrict__ Qf, const ushort_t* __restrict__ Kf,
    const ushort_t* __restrict__ Vt, const float4* __restrict__ QPn,
    const float4* __restrict__ KPn, ushort_t* __restrict__ O) {
  const int dsp = blockIdx.x;                  // 0..1023
  const int w = (dsp & 7) * 128 + (dsp >> 3);  // XCD-contiguous work id
  const int qp = w & 3, h = (w >> 2) & 15, b = w >> 6;
  const int tid = threadIdx.x, lane = tid & 63, wid = tid >> 6;
  const int lq = lane & 15, g = lane >> 4;
  const bool pen = (h >= HALF);
  const float slopeL = -exp2f(-0.5f * (float)(h + 1)) * L2E;
  const size_t hoff = ((size_t)b * H + h) * S * DK;
  const ushort_t* Vslab = Vt + hoff;  // [dk][s] bf16
  const size_t bhh = (size_t)b * HALF + (h & (HALF - 1));

  __shared__ __align__(16) char sK[2][8192];
  __shared__ __align__(16) char sV[2][8192];
  __shared__ __align__(16) float4 sPen[2][64];

  const int qb_hi = 7 - qp, qb_lo = qp;
  const int qgH = qb_hi * 64 + wid * 16 + lq;
  const int qgL = qb_lo * 64 + wid * 16 + lq;

  short8v qfH[2], qfL[2];
  {
    const ushort_t* qr = Qf + hoff + (size_t)qgH * DK;
    qfH[0] = *(const short8v*)(qr + g * 8);
    qfH[1] = *(const short8v*)(qr + 32 + g * 8);
    qr = Qf + hoff + (size_t)qgL * DK;
    qfL[0] = *(const short8v*)(qr + g * 8);
    qfL[1] = *(const short8v*)(qr + 32 + g * 8);
    if (pen && g == 3) { qfH[1][7] = 0; qfL[1][7] = 0; }  // drop y from dot
  }
  float qnH = 0, qy2H = 0, xqyH = 0, qnL = 0, qy2L = 0, xqyL = 0;
  if (pen) {
    const float4 a = QPn[bhh * S + qgH];
    qnH = a.x; qy2H = a.y; xqyH = a.z;
    const float4 c = QPn[bhh * S + qgL];
    qnL = c.x; qy2L = c.y; xqyL = c.z;
  }

  const int r8 = lane >> 3;
  const int sl = ((lane & 7) ^ r8) * 8;  // pre-swizzled 16B-granule offset

  auto stage = [&](int buf, int kt) {
#pragma unroll
    for (int i = 0; i < 2; ++i) {
      const int row = wid * 16 + i * 8 + r8;
      gload16(Kf + hoff + (size_t)(kt * 64 + row) * DK + sl,
              &sK[buf][(wid * 2 + i) * 1024]);
      gload16(Vslab + (size_t)row * S + kt * 64 + sl,
              &sV[buf][(wid * 2 + i) * 1024]);
    }
    if (pen && wid == 0)
      gload16(&KPn[bhh * S + kt * 64 + lane], &sPen[buf][0]);
  };

  f32x4 oH[4], oL[4];
#pragma unroll
  for (int dt = 0; dt < 4; ++dt) {
    oH[dt] = (f32x4){0.f, 0.f, 0.f, 0.f};
    oL[dt] = (f32x4){0.f, 0.f, 0.f, 0.f};
  }
  float mH = -1e30f, lH = 0.f, mL = -1e30f, lL = 0.f;

  stage(0, qb_hi);
  __syncthreads();
  int cur = 0;
  for (int kt = qb_hi; kt >= 0; --kt) {
    if (kt > 0) stage(cur ^ 1, kt - 1);
    if (kt == qb_hi)
      attn_tile<true>(sK[cur], sV[cur], sPen[cur], qfH, qnH, qy2H, xqyH, pen,
                      slopeL, qgH, kt * 64, lq, g, oH, mH, lH);
    else
      attn_tile<false>(sK[cur], sV[cur], sPen[cur], qfH, qnH, qy2H, xqyH, pen,
                       slopeL, qgH, kt * 64, lq, g, oH, mH, lH);
    if (kt <= qb_lo) {
      if (kt == qb_lo)
        attn_tile<true>(sK[cur], sV[cur], sPen[cur], qfL, qnL, qy2L, xqyL, pen,
                        slopeL, qgL, kt * 64, lq, g, oL, mL, lL);
      else
        attn_tile<false>(sK[cur], sV[cur], sPen[cur], qfL, qnL, qy2L, xqyL,
                         pen, slopeL, qgL, kt * 64, lq, g, oL, mL, lL);
    }
    __syncthreads();  // drains vmcnt: next buffer complete, cur free to reuse
    cur ^= 1;
  }

  const float invH = 1.0f / lH;  // qgH >= 256, always nonzero
  const float invL = (qgL == 0) ? 0.f : 1.0f / lL;
  ushort_t* orH = O + ((size_t)b * S + qgH) * D + h * DK;
  ushort_t* orL = O + ((size_t)b * S + qgL) * D + h * DK;
#pragma unroll
  for (int dt = 0; dt < 4; ++dt) {
    uint2 u;
    u.x = cvtpk(oH[dt][0] * invH, oH[dt][1] * invH);
    u.y = cvtpk(oH[dt][2] * invH, oH[dt][3] * invH);
    *(uint2*)(orH + dt * 16 + g * 4) = u;
    uint2 v;
    v.x = cvtpk(oL[dt][0] * invL, oL[dt][1] * invL);
    v.y = cvtpk(oL[dt][2] * invL, oL[dt][3] * invL);
    *(uint2*)(orL + dt * 16 + g * 4) = v;
  }
}

// ---------------------------------------------------------------------------
extern "C" void kernel_launch(void* const* d_in, const int* in_sizes, int n_in,
                              void* d_out, int out_size, void* d_ws,
                              size_t ws_size, hipStream_t stream) {
  (void)in_sizes; (void)n_in; (void)out_size; (void)ws_size;
  const float* x  = (const float*)d_in[0];
  const float* Wq = (const float*)d_in[1];
  const float* bq = (const float*)d_in[2];
  const float* Wk = (const float*)d_in[3];
  const float* bk = (const float*)d_in[4];
  const float* Wv = (const float*)d_in[5];
  const float* bv = (const float*)d_in[6];
  const float* Wo = (const float*)d_in[7];
  const float* bo = (const float*)d_in[8];
  float* out = (float*)d_out;

  const size_t NQKV = (size_t)BS * H * S * DK;  // 8388608
  const size_t NW = (size_t)D * D;              // 1048576
  ushort_t* ws  = (ushort_t*)d_ws;
  ushort_t* Qb  = ws;
  ushort_t* Kbb = Qb + NQKV;
  ushort_t* Vtb = Kbb + NQKV;
  ushort_t* Ob  = Vtb + NQKV;
  ushort_t* xb  = Ob + NQKV;
  ushort_t* Wqb = xb + NQKV;
  ushort_t* Wkb = Wqb + NW;
  ushort_t* Wvb = Wkb + NW;
  ushort_t* Wob = Wvb + NW;
  float4* QPn = (float4*)(Wob + NW);
  float4* KPn = QPn + (size_t)BS * HALF * S;

  cvt_bf16<<<dim3(4096), 256, 0, stream>>>(x, xb, (int)(NQKV / 8));
  cvt_bf16<<<dim3(512), 256, 0, stream>>>(Wq, Wqb, (int)(NW / 8));
  cvt_bf16<<<dim3(512), 256, 0, stream>>>(Wk, Wkb, (int)(NW / 8));
  cvt_bf16<<<dim3(512), 256, 0, stream>>>(Wv, Wvb, (int)(NW / 8));
  cvt_bf16<<<dim3(512), 256, 0, stream>>>(Wo, Wob, (int)(NW / 8));

  dim3 gg(8, 64);
  gemm_mfma<0><<<gg, 256, 0, stream>>>(xb, Wqb, bq, Qb);
  gemm_mfma<0><<<gg, 256, 0, stream>>>(xb, Wkb, bk, Kbb);
  gemm_mfma<1><<<gg, 256, 0, stream>>>(xb, Wvb, bv, Vtb);
  psi_kernel<<<dim3(S / 4, HALF, BS), 256, 0, stream>>>(Qb, QPn);
  psi_kernel<<<dim3(S / 4, HALF, BS), 256, 0, stream>>>(Kbb, KPn);
  attn_mfma<<<dim3(1024), 256, 0, stream>>>(Qb, Kbb, Vtb, QPn, KPn, Ob);
  gemm_mfma<2><<<gg, 256, 0, stream>>>(Ob, Wob, bo, out);
}

// Round 7
// 192.460 us; speedup vs baseline: 1.1695x; 1.1695x over previous
//
#include <hip/hip_runtime.h>
#include <math.h>

#define BS 16
#define S 512
#define D 1024
#define H 16
#define DK 64
#define HALF 8

typedef __attribute__((ext_vector_type(8))) short short8v;
typedef __attribute__((ext_vector_type(4))) float f32x4;
typedef unsigned short ushort_t;

#define L2E 1.4426950408889634f
#define SC_STD (0.125f * L2E)
#define SC_PEN (-0.0125f * L2E)

__device__ __forceinline__ ushort_t f2bf(float f) {
  union { float f; unsigned u; } v; v.f = f;
  unsigned r = v.u + 0x7fffu + ((v.u >> 16) & 1u);
  return (ushort_t)(r >> 16);
}
__device__ __forceinline__ unsigned packbf(float a, float b) {
  return (unsigned)f2bf(a) | ((unsigned)f2bf(b) << 16);
}
__device__ __forceinline__ float bf2f(ushort_t u) {
  union { unsigned u; float f; } v; v.u = ((unsigned)u) << 16;
  return v.f;
}
__device__ __forceinline__ unsigned cvtpk(float lo, float hi) {
  unsigned r;
  asm("v_cvt_pk_bf16_f32 %0, %1, %2" : "=v"(r) : "v"(lo), "v"(hi));
  return r;
}

__device__ __forceinline__ void gload16(const void* g, void* l) {
  __builtin_amdgcn_global_load_lds(
      (const __attribute__((address_space(1))) unsigned int*)g,
      (__attribute__((address_space(3))) unsigned int*)l, 16, 0, 0);
}

// ---------------------------------------------------------------------------
// f32 -> bf16 convert, 8 elems/thread
// ---------------------------------------------------------------------------
__global__ __launch_bounds__(256) void cvt_bf16(const float* __restrict__ in,
                                                ushort_t* __restrict__ out,
                                                int n8) {
  const int i = blockIdx.x * 256 + threadIdx.x;
  if (i >= n8) return;
  const float4 a = *(const float4*)(in + (size_t)i * 8);
  const float4 b = *(const float4*)(in + (size_t)i * 8 + 4);
  union { short8v v; unsigned u[4]; } t;
  t.u[0] = packbf(a.x, a.y);
  t.u[1] = packbf(a.z, a.w);
  t.u[2] = packbf(b.x, b.y);
  t.u[3] = packbf(b.z, b.w);
  *(short8v*)(out + (size_t)i * 8) = t.v;
}

// ---------------------------------------------------------------------------
// bf16 MFMA GEMM (unchanged): C[8192,1024] = A * B^T + bias
// ---------------------------------------------------------------------------
template <int EPI>
__global__ __launch_bounds__(256) void gemm_mfma(
    const ushort_t* __restrict__ A, const ushort_t* __restrict__ B,
    const float* __restrict__ bias, void* __restrict__ Cout) {
  const int tid = threadIdx.x;
  const int lane = tid & 63, wid = tid >> 6;
  const int wr = wid >> 1, wc = wid & 1;
  const int lq = lane & 15, g = lane >> 4;
  const int bn = blockIdx.x;
  const int bm = blockIdx.y;

  __shared__ __align__(16) ushort_t sA[128 * 64];
  __shared__ __align__(16) ushort_t sB[128 * 64];

  f32x4 acc[4][4];
#pragma unroll
  for (int i = 0; i < 4; i++)
#pragma unroll
    for (int j = 0; j < 4; j++) acc[i][j] = (f32x4){0.f, 0.f, 0.f, 0.f};

  for (int k0 = 0; k0 < 1024; k0 += 64) {
#pragma unroll
    for (int is = 0; is < 4; ++is) {
      const int gi = is * 256 + tid;
      const int row = gi >> 3, slot = gi & 7;
      const int sslot = slot ^ (row & 7);
      const ushort_t* srcA =
          A + (size_t)(bm * 128 + row) * 1024 + k0 + sslot * 8;
      const ushort_t* srcB =
          B + (size_t)(bn * 128 + row) * 1024 + k0 + sslot * 8;
      gload16(srcA, &sA[(is * 256 + wid * 64) * 8]);
      gload16(srcB, &sB[(is * 256 + wid * 64) * 8]);
    }
    __syncthreads();
#pragma unroll
    for (int ks = 0; ks < 2; ++ks) {
      short8v af[4], bf[4];
#pragma unroll
      for (int i = 0; i < 4; ++i) {
        const int arow = wr * 64 + i * 16 + lq;
        af[i] = *(const short8v*)&sA[arow * 64 + (((ks * 4 + g) ^ (arow & 7)) * 8)];
        const int brow = wc * 64 + i * 16 + lq;
        bf[i] = *(const short8v*)&sB[brow * 64 + (((ks * 4 + g) ^ (brow & 7)) * 8)];
      }
#pragma unroll
      for (int i = 0; i < 4; ++i)
#pragma unroll
        for (int j = 0; j < 4; ++j)
          acc[i][j] =
              __builtin_amdgcn_mfma_f32_16x16x32_bf16(af[i], bf[j], acc[i][j], 0, 0, 0);
    }
    __syncthreads();
  }

#pragma unroll
  for (int j = 0; j < 4; ++j) {
    const int n = bn * 128 + wc * 64 + j * 16 + lq;
    const float bv = bias[n];
#pragma unroll
    for (int i = 0; i < 4; ++i) {
      const int mb = bm * 128 + wr * 64 + i * 16 + g * 4;
      if (EPI == 0) {
        ushort_t* C = (ushort_t*)Cout;
#pragma unroll
        for (int r = 0; r < 4; ++r) {
          const int m = mb + r;
          const float c = acc[i][j][r] + bv;
          C[((((size_t)(m >> 9) * H + (n >> 6)) * S + (m & 511)) * DK) +
            (n & 63)] = f2bf(c);
        }
      } else if (EPI == 1) {
        ushort_t* C = (ushort_t*)Cout;
        const int bb = mb >> 9, s0 = mb & 511;
        uint2 u;
        u.x = packbf(acc[i][j][0] + bv, acc[i][j][1] + bv);
        u.y = packbf(acc[i][j][2] + bv, acc[i][j][3] + bv);
        *(uint2*)(C + (((size_t)bb * H + (n >> 6)) * DK + (n & 63)) * S + s0) = u;
      } else {
        float* C = (float*)Cout;
#pragma unroll
        for (int r = 0; r < 4; ++r)
          C[(size_t)(mb + r) * 1024 + n] = acc[i][j][r] + bv;
      }
    }
  }
}

// ---------------------------------------------------------------------------
// psi transform on bf16 (in place), heads HALF..H-1; emits per-row float4
// (sum(x^2, d<63), y^2, sqrt(1-y^2+eps), 0) for the penumbral score math.
// ---------------------------------------------------------------------------
__global__ __launch_bounds__(256) void psi_kernel(ushort_t* __restrict__ X,
                                                  float4* __restrict__ Pn) {
  const int s = blockIdx.x * 4 + (threadIdx.x >> 6);
  const int hh = blockIdx.y, b = blockIdx.z;
  const int h = HALF + hh;
  ushort_t* row = X + (((size_t)b * H + h) * S + s) * DK;
  const int t = threadIdx.x & 63;
  const float v = bf2f(row[t]);
  const float last = __shfl(v, 63, 64);
  const float y = 1.0f / (1.0f + expf(-last));
  const float xv = (t < 63) ? v * y : y;
  const ushort_t bvv = f2bf(xv);
  row[t] = bvv;
  const float xr = bf2f(bvv);
  float sq = (t < 63) ? xr * xr : 0.0f;
#pragma unroll
  for (int off = 32; off; off >>= 1) sq += __shfl_xor(sq, off, 64);
  if (t == 0)
    Pn[((size_t)b * HALF + hh) * S + s] =
        make_float4(sq, y * y, sqrtf(1.0f - y * y + 1e-6f), 0.0f);
}

// ---------------------------------------------------------------------------
// One q-tile update vs the currently staged 64-k tile. Log2-domain softmax.
// MASK: only the diagonal k-tile needs causal masking.
// ---------------------------------------------------------------------------
template <bool MASK>
__device__ __forceinline__ void attn_tile(
    const char* sKb, const char* sVb, const float4* sPn, const short8v* qf,
    float qn, float qy2, float xqy, bool pen, float slopeL, int qg, int kt0,
    int lq, int g, f32x4* o, float& m, float& lacc) {
  float p[4][4];
  float tmax = -1e30f;
#pragma unroll
  for (int t4 = 0; t4 < 4; ++t4) {
    f32x4 acc = (f32x4){0.f, 0.f, 0.f, 0.f};
    const int row = t4 * 16 + lq;
#pragma unroll
    for (int c = 0; c < 2; ++c) {
      const short8v ka =
          *(const short8v*)(sKb + row * 128 + (((c * 4 + g) ^ (row & 7)) * 16));
      acc = __builtin_amdgcn_mfma_f32_16x16x32_bf16(ka, qf[c], acc, 0, 0, 0);
    }
#pragma unroll
    for (int r = 0; r < 4; ++r) {
      const int kg = kt0 + t4 * 16 + g * 4 + r;
      const float abL = slopeL * (float)(qg - kg);
      float s;
      if (!pen) {
        s = acc[r] * SC_STD + abL;
      } else {
        const float4 kp = sPn[t4 * 16 + g * 4 + r];
        const float kn = kp.x, ky2 = kp.y, xky = kp.z;
        const float d2 = qn + kn - 2.0f * acc[r];
        const float tt = fmaxf(d2, 0.0f) + 1e-12f;
        const float rs = rsqrtf(tt);
        const float pd = tt * rs;  // = sqrt(tt)
        const float tmp = (xqy + xky - pd) * 0.5f;
        const float lca = fmaxf(fmaxf(qy2, ky2), 1.0f - tmp * tmp);
        const float num = (d2 + ky2 - qy2) * (0.5f * rs);
        const float lout = num * num + qy2;
        const float dxy = pd - xqy;
        const bool ex = (pd <= xqy) || (dxy * dxy + ky2 <= 1.0f);
        s = (ex ? lca : lout) * SC_PEN + abL;
      }
      if (MASK && kg >= qg) s = -1e30f;
      p[t4][r] = s;
      tmax = fmaxf(tmax, s);
    }
  }
  tmax = fmaxf(tmax, __shfl_xor(tmax, 16, 64));
  tmax = fmaxf(tmax, __shfl_xor(tmax, 32, 64));
  const float mnew = fmaxf(m, tmax);
  if (__any(mnew > m)) {  // diagonal-first order: usually only taken once
    const float fsc = exp2f(m - mnew);
#pragma unroll
    for (int dt = 0; dt < 4; ++dt) o[dt] *= fsc;
    lacc *= fsc;
    m = mnew;
  }
  float ls = 0.f;
#pragma unroll
  for (int t4 = 0; t4 < 4; ++t4)
#pragma unroll
    for (int r = 0; r < 4; ++r) {
      float pv = exp2f(p[t4][r] - m);
      if (MASK && p[t4][r] < -1e29f) pv = 0.f;
      p[t4][r] = pv;
      ls += pv;
    }
  ls += __shfl_xor(ls, 16, 64);
  ls += __shfl_xor(ls, 32, 64);
  lacc += ls;

  unsigned pk0[4], pk1[4];
#pragma unroll
  for (int t4 = 0; t4 < 4; ++t4) {
    pk0[t4] = cvtpk(p[t4][0], p[t4][1]);
    pk1[t4] = cvtpk(p[t4][2], p[t4][3]);
  }
  const int s0 = lq | (((g * 2) & 3) << 4);
  const int s1 = lq | (((g * 2 + 1) & 3) << 4);
  const bool hi = (g >= 2);
#pragma unroll
  for (int c = 0; c < 2; ++c) {
    const unsigned a0 = (unsigned)__shfl((int)pk0[2 * c], s0, 64);
    const unsigned b0 = (unsigned)__shfl((int)pk0[2 * c + 1], s0, 64);
    const unsigned a1 = (unsigned)__shfl((int)pk1[2 * c], s0, 64);
    const unsigned b1 = (unsigned)__shfl((int)pk1[2 * c + 1], s0, 64);
    const unsigned a2 = (unsigned)__shfl((int)pk0[2 * c], s1, 64);
    const unsigned b2 = (unsigned)__shfl((int)pk0[2 * c + 1], s1, 64);
    const unsigned a3 = (unsigned)__shfl((int)pk1[2 * c], s1, 64);
    const unsigned b3 = (unsigned)__shfl((int)pk1[2 * c + 1], s1, 64);
    union { short8v v; unsigned u[4]; } pb;
    pb.u[0] = hi ? b0 : a0;
    pb.u[1] = hi ? b1 : a1;
    pb.u[2] = hi ? b2 : a2;
    pb.u[3] = hi ? b3 : a3;
#pragma unroll
    for (int dt = 0; dt < 4; ++dt) {
      const int vr = dt * 16 + lq;
      const short8v va =
          *(const short8v*)(sVb + vr * 128 + (((c * 4 + g) ^ (vr & 7)) * 16));
      o[dt] = __builtin_amdgcn_mfma_f32_16x16x32_bf16(va, pb.v, o[dt], 0, 0, 0);
    }
  }
}

// ---------------------------------------------------------------------------
// Flash attention: ONE 64-row q-tile per block (single context -> ~half the
// per-wave registers of the R5/R6 dual-context version, which was stuck at
// ~1.25 blocks/CU). Grid 2048: decode keeps all 8 q-tiles of a (b,h) on one
// XCD (L2 reuse: 32 slabs x 128KB = 4MB/XCD) and dispatches large-qb blocks
// first so short blocks backfill the causal-skew tail.
// ---------------------------------------------------------------------------
__global__ __launch_bounds__(256, 3) void attn_mfma(
    const ushort_t* __restrict__ Qf, const ushort_t* __restrict__ Kf,
    const ushort_t* __restrict__ Vt, const float4* __restrict__ QPn,
    const float4* __restrict__ KPn, ushort_t* __restrict__ O) {
  const int dsp = blockIdx.x;  // 0..2047
  const int xcd = dsp & 7, idx = dsp >> 3;
  const int bh = xcd * 32 + (idx & 31);
  const int qb = 7 - (idx >> 5);  // big q-tiles dispatched first
  const int b = bh >> 4, h = bh & 15;
  const int tid = threadIdx.x, lane = tid & 63, wid = tid >> 6;
  const int lq = lane & 15, g = lane >> 4;
  const bool pen = (h >= HALF);
  const float slopeL = -exp2f(-0.5f * (float)(h + 1)) * L2E;
  const size_t hoff = ((size_t)b * H + h) * S * DK;
  const ushort_t* Vslab = Vt + hoff;  // [dk][s] bf16
  const size_t bhh = (size_t)b * HALF + (h & (HALF - 1));

  __shared__ __align__(16) char sK[2][8192];
  __shared__ __align__(16) char sV[2][8192];
  __shared__ __align__(16) float4 sPen[2][64];

  const int qg = qb * 64 + wid * 16 + lq;

  short8v qf[2];
  {
    const ushort_t* qr = Qf + hoff + (size_t)qg * DK;
    qf[0] = *(const short8v*)(qr + g * 8);
    qf[1] = *(const short8v*)(qr + 32 + g * 8);
    if (pen && g == 3) qf[1][7] = 0;  // drop y from the MFMA dot
  }
  float qn = 0, qy2 = 0, xqy = 0;
  if (pen) {
    const float4 a = QPn[bhh * S + qg];
    qn = a.x; qy2 = a.y; xqy = a.z;
  }

  const int r8 = lane >> 3;
  const int sl = ((lane & 7) ^ r8) * 8;  // pre-swizzled 16B-granule offset

  auto stage = [&](int buf, int kt) {
#pragma unroll
    for (int i = 0; i < 2; ++i) {
      const int row = wid * 16 + i * 8 + r8;
      gload16(Kf + hoff + (size_t)(kt * 64 + row) * DK + sl,
              &sK[buf][(wid * 2 + i) * 1024]);
      gload16(Vslab + (size_t)row * S + kt * 64 + sl,
              &sV[buf][(wid * 2 + i) * 1024]);
    }
    if (pen && wid == 0)
      gload16(&KPn[bhh * S + kt * 64 + lane], &sPen[buf][0]);
  };

  f32x4 o[4];
#pragma unroll
  for (int dt = 0; dt < 4; ++dt) o[dt] = (f32x4){0.f, 0.f, 0.f, 0.f};
  float m = -1e30f, l = 0.f;

  stage(0, qb);
  __syncthreads();
  int cur = 0;
  for (int kt = qb; kt >= 0; --kt) {
    if (kt > 0) stage(cur ^ 1, kt - 1);
    if (kt == qb)
      attn_tile<true>(sK[cur], sV[cur], sPen[cur], qf, qn, qy2, xqy, pen,
                      slopeL, qg, kt * 64, lq, g, o, m, l);
    else
      attn_tile<false>(sK[cur], sV[cur], sPen[cur], qf, qn, qy2, xqy, pen,
                       slopeL, qg, kt * 64, lq, g, o, m, l);
    __syncthreads();  // drains vmcnt: next buffer complete, cur free to reuse
    cur ^= 1;
  }

  const float invl = (qg == 0) ? 0.f : 1.0f / l;
  ushort_t* orow = O + ((size_t)b * S + qg) * D + h * DK;
#pragma unroll
  for (int dt = 0; dt < 4; ++dt) {
    uint2 u;
    u.x = cvtpk(o[dt][0] * invl, o[dt][1] * invl);
    u.y = cvtpk(o[dt][2] * invl, o[dt][3] * invl);
    *(uint2*)(orow + dt * 16 + g * 4) = u;
  }
}

// ---------------------------------------------------------------------------
extern "C" void kernel_launch(void* const* d_in, const int* in_sizes, int n_in,
                              void* d_out, int out_size, void* d_ws,
                              size_t ws_size, hipStream_t stream) {
  (void)in_sizes; (void)n_in; (void)out_size; (void)ws_size;
  const float* x  = (const float*)d_in[0];
  const float* Wq = (const float*)d_in[1];
  const float* bq = (const float*)d_in[2];
  const float* Wk = (const float*)d_in[3];
  const float* bk = (const float*)d_in[4];
  const float* Wv = (const float*)d_in[5];
  const float* bv = (const float*)d_in[6];
  const float* Wo = (const float*)d_in[7];
  const float* bo = (const float*)d_in[8];
  float* out = (float*)d_out;

  const size_t NQKV = (size_t)BS * H * S * DK;  // 8388608
  const size_t NW = (size_t)D * D;              // 1048576
  ushort_t* ws  = (ushort_t*)d_ws;
  ushort_t* Qb  = ws;
  ushort_t* Kbb = Qb + NQKV;
  ushort_t* Vtb = Kbb + NQKV;
  ushort_t* Ob  = Vtb + NQKV;
  ushort_t* xb  = Ob + NQKV;
  ushort_t* Wqb = xb + NQKV;
  ushort_t* Wkb = Wqb + NW;
  ushort_t* Wvb = Wkb + NW;
  ushort_t* Wob = Wvb + NW;
  float4* QPn = (float4*)(Wob + NW);
  float4* KPn = QPn + (size_t)BS * HALF * S;

  cvt_bf16<<<dim3(4096), 256, 0, stream>>>(x, xb, (int)(NQKV / 8));
  cvt_bf16<<<dim3(512), 256, 0, stream>>>(Wq, Wqb, (int)(NW / 8));
  cvt_bf16<<<dim3(512), 256, 0, stream>>>(Wk, Wkb, (int)(NW / 8));
  cvt_bf16<<<dim3(512), 256, 0, stream>>>(Wv, Wvb, (int)(NW / 8));
  cvt_bf16<<<dim3(512), 256, 0, stream>>>(Wo, Wob, (int)(NW / 8));

  dim3 gg(8, 64);
  gemm_mfma<0><<<gg, 256, 0, stream>>>(xb, Wqb, bq, Qb);
  gemm_mfma<0><<<gg, 256, 0, stream>>>(xb, Wkb, bk, Kbb);
  gemm_mfma<1><<<gg, 256, 0, stream>>>(xb, Wvb, bv, Vtb);
  psi_kernel<<<dim3(S / 4, HALF, BS), 256, 0, stream>>>(Qb, QPn);
  psi_kernel<<<dim3(S / 4, HALF, BS), 256, 0, stream>>>(Kbb, KPn);
  attn_mfma<<<dim3(2048), 256, 0, stream>>>(Qb, Kbb, Vtb, QPn, KPn, Ob);
  gemm_mfma<2><<<gg, 256, 0, stream>>>(Ob, Wob, bo, out);
}

// Round 8
// 171.559 us; speedup vs baseline: 1.3120x; 1.1218x over previous
//
#include <hip/hip_runtime.h>
#include <math.h>

#define BS 16
#define S 512
#define D 1024
#define H 16
#define DK 64
#define HALF 8

typedef __attribute__((ext_vector_type(8))) short short8v;
typedef __attribute__((ext_vector_type(4))) float f32x4;
typedef unsigned short ushort_t;

#define L2E 1.4426950408889634f
#define SC_STD (0.125f * L2E)
#define SC_PEN (-0.0125f * L2E)

__device__ __forceinline__ ushort_t f2bf(float f) {
  union { float f; unsigned u; } v; v.f = f;
  unsigned r = v.u + 0x7fffu + ((v.u >> 16) & 1u);
  return (ushort_t)(r >> 16);
}
__device__ __forceinline__ unsigned packbf(float a, float b) {
  return (unsigned)f2bf(a) | ((unsigned)f2bf(b) << 16);
}
__device__ __forceinline__ float bf2f(ushort_t u) {
  union { unsigned u; float f; } v; v.u = ((unsigned)u) << 16;
  return v.f;
}
__device__ __forceinline__ unsigned cvtpk(float lo, float hi) {
  unsigned r;
  asm("v_cvt_pk_bf16_f32 %0, %1, %2" : "=v"(r) : "v"(lo), "v"(hi));
  return r;
}

__device__ __forceinline__ void gload16(const void* g, void* l) {
  __builtin_amdgcn_global_load_lds(
      (const __attribute__((address_space(1))) unsigned int*)g,
      (__attribute__((address_space(3))) unsigned int*)l, 16, 0, 0);
}

// ---------------------------------------------------------------------------
// fused f32 -> bf16 convert: x (4096 blocks) then Wq/Wk/Wv/Wo (512 each).
// Destinations are CONTIGUOUS in ws (xb,Wqb,Wkb,Wvb,Wob), so dst is linear.
// ---------------------------------------------------------------------------
__global__ __launch_bounds__(256) void cvt_fused(
    const float* __restrict__ x, const float* __restrict__ Wq,
    const float* __restrict__ Wk, const float* __restrict__ Wv,
    const float* __restrict__ Wo, ushort_t* __restrict__ dst) {
  const int bid = blockIdx.x;
  const float* src;
  int si;
  if (bid < 4096) {
    src = x; si = bid * 256 + threadIdx.x;
  } else {
    const int k = bid - 4096;
    const int w = k >> 9;
    src = (w == 0) ? Wq : (w == 1) ? Wk : (w == 2) ? Wv : Wo;
    si = (k & 511) * 256 + threadIdx.x;
  }
  const int di = bid * 256 + threadIdx.x;
  const float4 a = *(const float4*)(src + (size_t)si * 8);
  const float4 b = *(const float4*)(src + (size_t)si * 8 + 4);
  union { short8v v; unsigned u[4]; } t;
  t.u[0] = packbf(a.x, a.y);
  t.u[1] = packbf(a.z, a.w);
  t.u[2] = packbf(b.x, b.y);
  t.u[3] = packbf(b.z, b.w);
  *(short8v*)(dst + (size_t)di * 8) = t.v;
}

// ---------------------------------------------------------------------------
// Fused QKV GEMM: C[8192, 3072] = x * [Wq;Wk;Wv]^T + bias.
// bn 0..7 -> Q (head layout), 8..15 -> K (head layout), 16..23 -> V^T.
// ---------------------------------------------------------------------------
__global__ __launch_bounds__(256) void gemm_qkv(
    const ushort_t* __restrict__ A, const ushort_t* __restrict__ Wcat,
    const float* __restrict__ bq, const float* __restrict__ bk,
    const float* __restrict__ bv, ushort_t* __restrict__ QK,
    ushort_t* __restrict__ Vt) {
  const int tid = threadIdx.x;
  const int lane = tid & 63, wid = tid >> 6;
  const int wr = wid >> 1, wc = wid & 1;
  const int lq = lane & 15, g = lane >> 4;
  const int bn = blockIdx.x;  // 0..23
  const int bm = blockIdx.y;  // 0..63
  const int mat = bn >> 3;    // 0=Q 1=K 2=V

  __shared__ __align__(16) ushort_t sA[128 * 64];
  __shared__ __align__(16) ushort_t sB[128 * 64];

  f32x4 acc[4][4];
#pragma unroll
  for (int i = 0; i < 4; i++)
#pragma unroll
    for (int j = 0; j < 4; j++) acc[i][j] = (f32x4){0.f, 0.f, 0.f, 0.f};

  for (int k0 = 0; k0 < 1024; k0 += 64) {
#pragma unroll
    for (int is = 0; is < 4; ++is) {
      const int gi = is * 256 + tid;
      const int row = gi >> 3, slot = gi & 7;
      const int sslot = slot ^ (row & 7);
      gload16(A + (size_t)(bm * 128 + row) * 1024 + k0 + sslot * 8,
              &sA[(is * 256 + wid * 64) * 8]);
      gload16(Wcat + (size_t)(bn * 128 + row) * 1024 + k0 + sslot * 8,
              &sB[(is * 256 + wid * 64) * 8]);
    }
    __syncthreads();
#pragma unroll
    for (int ks = 0; ks < 2; ++ks) {
      short8v af[4], bf[4];
#pragma unroll
      for (int i = 0; i < 4; ++i) {
        const int arow = wr * 64 + i * 16 + lq;
        af[i] = *(const short8v*)&sA[arow * 64 + (((ks * 4 + g) ^ (arow & 7)) * 8)];
        const int brow = wc * 64 + i * 16 + lq;
        bf[i] = *(const short8v*)&sB[brow * 64 + (((ks * 4 + g) ^ (brow & 7)) * 8)];
      }
#pragma unroll
      for (int i = 0; i < 4; ++i)
#pragma unroll
        for (int j = 0; j < 4; ++j)
          acc[i][j] =
              __builtin_amdgcn_mfma_f32_16x16x32_bf16(af[i], bf[j], acc[i][j], 0, 0, 0);
    }
    __syncthreads();
  }

  const float* bias = (mat == 0) ? bq : (mat == 1) ? bk : bv;
  const size_t NQKV = (size_t)BS * H * S * DK;
#pragma unroll
  for (int j = 0; j < 4; ++j) {
    const int n = ((bn & 7) * 128) + wc * 64 + j * 16 + lq;  // 0..1023 in-matrix
    const float bvv = bias[n];
#pragma unroll
    for (int i = 0; i < 4; ++i) {
      const int mb = bm * 128 + wr * 64 + i * 16 + g * 4;
      if (mat < 2) {
        ushort_t* C = QK + (size_t)mat * NQKV;
#pragma unroll
        for (int r = 0; r < 4; ++r) {
          const int m = mb + r;
          C[((((size_t)(m >> 9) * H + (n >> 6)) * S + (m & 511)) * DK) +
            (n & 63)] = f2bf(acc[i][j][r] + bvv);
        }
      } else {
        const int bb = mb >> 9, s0 = mb & 511;
        uint2 u;
        u.x = packbf(acc[i][j][0] + bvv, acc[i][j][1] + bvv);
        u.y = packbf(acc[i][j][2] + bvv, acc[i][j][3] + bvv);
        *(uint2*)(Vt + (((size_t)bb * H + (n >> 6)) * DK + (n & 63)) * S + s0) = u;
      }
    }
  }
}

// ---------------------------------------------------------------------------
// bf16 MFMA GEMM for out-proj: C_f32[8192,1024] = A * B^T + bias
// ---------------------------------------------------------------------------
__global__ __launch_bounds__(256) void gemm_out(
    const ushort_t* __restrict__ A, const ushort_t* __restrict__ B,
    const float* __restrict__ bias, float* __restrict__ C) {
  const int tid = threadIdx.x;
  const int lane = tid & 63, wid = tid >> 6;
  const int wr = wid >> 1, wc = wid & 1;
  const int lq = lane & 15, g = lane >> 4;
  const int bn = blockIdx.x;
  const int bm = blockIdx.y;

  __shared__ __align__(16) ushort_t sA[128 * 64];
  __shared__ __align__(16) ushort_t sB[128 * 64];

  f32x4 acc[4][4];
#pragma unroll
  for (int i = 0; i < 4; i++)
#pragma unroll
    for (int j = 0; j < 4; j++) acc[i][j] = (f32x4){0.f, 0.f, 0.f, 0.f};

  for (int k0 = 0; k0 < 1024; k0 += 64) {
#pragma unroll
    for (int is = 0; is < 4; ++is) {
      const int gi = is * 256 + tid;
      const int row = gi >> 3, slot = gi & 7;
      const int sslot = slot ^ (row & 7);
      gload16(A + (size_t)(bm * 128 + row) * 1024 + k0 + sslot * 8,
              &sA[(is * 256 + wid * 64) * 8]);
      gload16(B + (size_t)(bn * 128 + row) * 1024 + k0 + sslot * 8,
              &sB[(is * 256 + wid * 64) * 8]);
    }
    __syncthreads();
#pragma unroll
    for (int ks = 0; ks < 2; ++ks) {
      short8v af[4], bf[4];
#pragma unroll
      for (int i = 0; i < 4; ++i) {
        const int arow = wr * 64 + i * 16 + lq;
        af[i] = *(const short8v*)&sA[arow * 64 + (((ks * 4 + g) ^ (arow & 7)) * 8)];
        const int brow = wc * 64 + i * 16 + lq;
        bf[i] = *(const short8v*)&sB[brow * 64 + (((ks * 4 + g) ^ (brow & 7)) * 8)];
      }
#pragma unroll
      for (int i = 0; i < 4; ++i)
#pragma unroll
        for (int j = 0; j < 4; ++j)
          acc[i][j] =
              __builtin_amdgcn_mfma_f32_16x16x32_bf16(af[i], bf[j], acc[i][j], 0, 0, 0);
    }
    __syncthreads();
  }

#pragma unroll
  for (int j = 0; j < 4; ++j) {
    const int n = bn * 128 + wc * 64 + j * 16 + lq;
    const float bvv = bias[n];
#pragma unroll
    for (int i = 0; i < 4; ++i) {
      const int mb = bm * 128 + wr * 64 + i * 16 + g * 4;
#pragma unroll
      for (int r = 0; r < 4; ++r)
        C[(size_t)(mb + r) * 1024 + n] = acc[i][j][r] + bvv;
    }
  }
}

// ---------------------------------------------------------------------------
// psi transform for Q and K in one launch (blockIdx.y: 0-7 Q heads, 8-15 K).
// ---------------------------------------------------------------------------
__global__ __launch_bounds__(256) void psi_kernel(
    ushort_t* __restrict__ Q, ushort_t* __restrict__ K,
    float4* __restrict__ QPn, float4* __restrict__ KPn) {
  const int s = blockIdx.x * 4 + (threadIdx.x >> 6);
  const int yy = blockIdx.y, b = blockIdx.z;
  const int isK = yy >> 3, hh = yy & 7;
  ushort_t* X = isK ? K : Q;
  float4* Pn = isK ? KPn : QPn;
  const int h = HALF + hh;
  ushort_t* row = X + (((size_t)b * H + h) * S + s) * DK;
  const int t = threadIdx.x & 63;
  const float v = bf2f(row[t]);
  const float last = __shfl(v, 63, 64);
  const float y = 1.0f / (1.0f + expf(-last));
  const float xv = (t < 63) ? v * y : y;
  const ushort_t bvv = f2bf(xv);
  row[t] = bvv;
  const float xr = bf2f(bvv);
  float sq = (t < 63) ? xr * xr : 0.0f;
#pragma unroll
  for (int off = 32; off; off >>= 1) sq += __shfl_xor(sq, off, 64);
  if (t == 0)
    Pn[((size_t)b * HALF + hh) * S + s] =
        make_float4(sq, y * y, sqrtf(1.0f - y * y + 1e-6f), 0.0f);
}

// ---------------------------------------------------------------------------
// One q-tile update vs the currently staged 64-k tile. Log2-domain softmax.
// ---------------------------------------------------------------------------
template <bool MASK>
__device__ __forceinline__ void attn_tile(
    const char* sKb, const char* sVb, const float4* sPn, const short8v* qf,
    float qn, float qy2, float xqy, bool pen, float slopeL, int qg, int kt0,
    int lq, int g, f32x4* o, float& m, float& lacc) {
  float p[4][4];
  float tmax = -1e30f;
#pragma unroll
  for (int t4 = 0; t4 < 4; ++t4) {
    f32x4 acc = (f32x4){0.f, 0.f, 0.f, 0.f};
    const int row = t4 * 16 + lq;
#pragma unroll
    for (int c = 0; c < 2; ++c) {
      const short8v ka =
          *(const short8v*)(sKb + row * 128 + (((c * 4 + g) ^ (row & 7)) * 16));
      acc = __builtin_amdgcn_mfma_f32_16x16x32_bf16(ka, qf[c], acc, 0, 0, 0);
    }
#pragma unroll
    for (int r = 0; r < 4; ++r) {
      const int kg = kt0 + t4 * 16 + g * 4 + r;
      const float abL = slopeL * (float)(qg - kg);
      float s;
      if (!pen) {
        s = acc[r] * SC_STD + abL;
      } else {
        const float4 kp = sPn[t4 * 16 + g * 4 + r];
        const float kn = kp.x, ky2 = kp.y, xky = kp.z;
        const float d2 = qn + kn - 2.0f * acc[r];
        const float tt = fmaxf(d2, 0.0f) + 1e-12f;
        const float rs = rsqrtf(tt);
        const float pd = tt * rs;  // = sqrt(tt)
        const float tmp = (xqy + xky - pd) * 0.5f;
        const float lca = fmaxf(fmaxf(qy2, ky2), 1.0f - tmp * tmp);
        const float num = (d2 + ky2 - qy2) * (0.5f * rs);
        const float lout = num * num + qy2;
        const float dxy = pd - xqy;
        const bool ex = (pd <= xqy) || (dxy * dxy + ky2 <= 1.0f);
        s = (ex ? lca : lout) * SC_PEN + abL;
      }
      if (MASK && kg >= qg) s = -1e30f;
      p[t4][r] = s;
      tmax = fmaxf(tmax, s);
    }
  }
  tmax = fmaxf(tmax, __shfl_xor(tmax, 16, 64));
  tmax = fmaxf(tmax, __shfl_xor(tmax, 32, 64));
  const float mnew = fmaxf(m, tmax);
  if (__any(mnew > m)) {  // diagonal-first order: usually only taken once
    const float fsc = exp2f(m - mnew);
#pragma unroll
    for (int dt = 0; dt < 4; ++dt) o[dt] *= fsc;
    lacc *= fsc;
    m = mnew;
  }
  float ls = 0.f;
#pragma unroll
  for (int t4 = 0; t4 < 4; ++t4)
#pragma unroll
    for (int r = 0; r < 4; ++r) {
      float pv = exp2f(p[t4][r] - m);
      if (MASK && p[t4][r] < -1e29f) pv = 0.f;
      p[t4][r] = pv;
      ls += pv;
    }
  ls += __shfl_xor(ls, 16, 64);
  ls += __shfl_xor(ls, 32, 64);
  lacc += ls;

  unsigned pk0[4], pk1[4];
#pragma unroll
  for (int t4 = 0; t4 < 4; ++t4) {
    pk0[t4] = cvtpk(p[t4][0], p[t4][1]);
    pk1[t4] = cvtpk(p[t4][2], p[t4][3]);
  }
  const int s0 = lq | (((g * 2) & 3) << 4);
  const int s1 = lq | (((g * 2 + 1) & 3) << 4);
  const bool hi = (g >= 2);
#pragma unroll
  for (int c = 0; c < 2; ++c) {
    const unsigned a0 = (unsigned)__shfl((int)pk0[2 * c], s0, 64);
    const unsigned b0 = (unsigned)__shfl((int)pk0[2 * c + 1], s0, 64);
    const unsigned a1 = (unsigned)__shfl((int)pk1[2 * c], s0, 64);
    const unsigned b1 = (unsigned)__shfl((int)pk1[2 * c + 1], s0, 64);
    const unsigned a2 = (unsigned)__shfl((int)pk0[2 * c], s1, 64);
    const unsigned b2 = (unsigned)__shfl((int)pk0[2 * c + 1], s1, 64);
    const unsigned a3 = (unsigned)__shfl((int)pk1[2 * c], s1, 64);
    const unsigned b3 = (unsigned)__shfl((int)pk1[2 * c + 1], s1, 64);
    union { short8v v; unsigned u[4]; } pb;
    pb.u[0] = hi ? b0 : a0;
    pb.u[1] = hi ? b1 : a1;
    pb.u[2] = hi ? b2 : a2;
    pb.u[3] = hi ? b3 : a3;
#pragma unroll
    for (int dt = 0; dt < 4; ++dt) {
      const int vr = dt * 16 + lq;
      const short8v va =
          *(const short8v*)(sVb + vr * 128 + (((c * 4 + g) ^ (vr & 7)) * 16));
      o[dt] = __builtin_amdgcn_mfma_f32_16x16x32_bf16(va, pb.v, o[dt], 0, 0, 0);
    }
  }
}

// ---------------------------------------------------------------------------
// Flash attention: one 64-row q-tile per block, descending causal k-tiles,
// double-buffered global_load_lds staging, XCD-contiguous work decode.
// (256,4): one step beyond R7's (256,3) (34% occ, no spill at ~170 regs).
// Forces ~128 total regs -> 4 waves/SIMD if the squeeze holds spill-free.
// Tripwire: WRITE_SIZE (16MB now) jumps if the allocator spills.
// ---------------------------------------------------------------------------
__global__ __launch_bounds__(256, 4) void attn_mfma(
    const ushort_t* __restrict__ Qf, const ushort_t* __restrict__ Kf,
    const ushort_t* __restrict__ Vt, const float4* __restrict__ QPn,
    const float4* __restrict__ KPn, ushort_t* __restrict__ O) {
  const int dsp = blockIdx.x;  // 0..2047
  const int xcd = dsp & 7, idx = dsp >> 3;
  const int bh = xcd * 32 + (idx & 31);
  const int qb = 7 - (idx >> 5);  // big q-tiles dispatched first
  const int b = bh >> 4, h = bh & 15;
  const int tid = threadIdx.x, lane = tid & 63, wid = tid >> 6;
  const int lq = lane & 15, g = lane >> 4;
  const bool pen = (h >= HALF);
  const float slopeL = -exp2f(-0.5f * (float)(h + 1)) * L2E;
  const size_t hoff = ((size_t)b * H + h) * S * DK;
  const ushort_t* Vslab = Vt + hoff;  // [dk][s] bf16
  const size_t bhh = (size_t)b * HALF + (h & (HALF - 1));

  __shared__ __align__(16) char sK[2][8192];
  __shared__ __align__(16) char sV[2][8192];
  __shared__ __align__(16) float4 sPen[2][64];

  const int qg = qb * 64 + wid * 16 + lq;

  short8v qf[2];
  {
    const ushort_t* qr = Qf + hoff + (size_t)qg * DK;
    qf[0] = *(const short8v*)(qr + g * 8);
    qf[1] = *(const short8v*)(qr + 32 + g * 8);
    if (pen && g == 3) qf[1][7] = 0;  // drop y from the MFMA dot
  }
  float qn = 0, qy2 = 0, xqy = 0;
  if (pen) {
    const float4 a = QPn[bhh * S + qg];
    qn = a.x; qy2 = a.y; xqy = a.z;
  }

  const int r8 = lane >> 3;
  const int sl = ((lane & 7) ^ r8) * 8;  // pre-swizzled 16B-granule offset

  auto stage = [&](int buf, int kt) {
#pragma unroll
    for (int i = 0; i < 2; ++i) {
      const int row = wid * 16 + i * 8 + r8;
      gload16(Kf + hoff + (size_t)(kt * 64 + row) * DK + sl,
              &sK[buf][(wid * 2 + i) * 1024]);
      gload16(Vslab + (size_t)row * S + kt * 64 + sl,
              &sV[buf][(wid * 2 + i) * 1024]);
    }
    if (pen && wid == 0)
      gload16(&KPn[bhh * S + kt * 64 + lane], &sPen[buf][0]);
  };

  f32x4 o[4];
#pragma unroll
  for (int dt = 0; dt < 4; ++dt) o[dt] = (f32x4){0.f, 0.f, 0.f, 0.f};
  float m = -1e30f, l = 0.f;

  stage(0, qb);
  __syncthreads();
  int cur = 0;
  for (int kt = qb; kt >= 0; --kt) {
    if (kt > 0) stage(cur ^ 1, kt - 1);
    if (kt == qb)
      attn_tile<true>(sK[cur], sV[cur], sPen[cur], qf, qn, qy2, xqy, pen,
                      slopeL, qg, kt * 64, lq, g, o, m, l);
    else
      attn_tile<false>(sK[cur], sV[cur], sPen[cur], qf, qn, qy2, xqy, pen,
                       slopeL, qg, kt * 64, lq, g, o, m, l);
    __syncthreads();  // drains vmcnt: next buffer complete, cur free to reuse
    cur ^= 1;
  }

  const float invl = (qg == 0) ? 0.f : 1.0f / l;
  ushort_t* orow = O + ((size_t)b * S + qg) * D + h * DK;
#pragma unroll
  for (int dt = 0; dt < 4; ++dt) {
    uint2 u;
    u.x = cvtpk(o[dt][0] * invl, o[dt][1] * invl);
    u.y = cvtpk(o[dt][2] * invl, o[dt][3] * invl);
    *(uint2*)(orow + dt * 16 + g * 4) = u;
  }
}

// ---------------------------------------------------------------------------
extern "C" void kernel_launch(void* const* d_in, const int* in_sizes, int n_in,
                              void* d_out, int out_size, void* d_ws,
                              size_t ws_size, hipStream_t stream) {
  (void)in_sizes; (void)n_in; (void)out_size; (void)ws_size;
  const float* x  = (const float*)d_in[0];
  const float* Wq = (const float*)d_in[1];
  const float* bq = (const float*)d_in[2];
  const float* Wk = (const float*)d_in[3];
  const float* bk = (const float*)d_in[4];
  const float* Wv = (const float*)d_in[5];
  const float* bv = (const float*)d_in[6];
  const float* Wo = (const float*)d_in[7];
  const float* bo = (const float*)d_in[8];
  float* out = (float*)d_out;

  const size_t NQKV = (size_t)BS * H * S * DK;  // 8388608
  const size_t NW = (size_t)D * D;              // 1048576
  ushort_t* ws  = (ushort_t*)d_ws;
  ushort_t* Qb  = ws;
  ushort_t* Kbb = Qb + NQKV;
  ushort_t* Vtb = Kbb + NQKV;
  ushort_t* Ob  = Vtb + NQKV;
  ushort_t* xb  = Ob + NQKV;   // xb..Wob contiguous: cvt_fused dst is linear
  ushort_t* Wqb = xb + NQKV;
  ushort_t* Wkb = Wqb + NW;
  ushort_t* Wvb = Wkb + NW;
  ushort_t* Wob = Wvb + NW;
  float4* QPn = (float4*)(Wob + NW);
  float4* KPn = QPn + (size_t)BS * HALF * S;

  cvt_fused<<<dim3(4096 + 4 * 512), 256, 0, stream>>>(x, Wq, Wk, Wv, Wo, xb);
  gemm_qkv<<<dim3(24, 64), 256, 0, stream>>>(xb, Wqb, bq, bk, bv, Qb, Vtb);
  psi_kernel<<<dim3(S / 4, 16, BS), 256, 0, stream>>>(Qb, Kbb, QPn, KPn);
  attn_mfma<<<dim3(2048), 256, 0, stream>>>(Qb, Kbb, Vtb, QPn, KPn, Ob);
  gemm_out<<<dim3(8, 64), 256, 0, stream>>>(Ob, Wob, bo, out);
}